// Round 7
// baseline (1893.319 us; speedup 1.0000x reference)
//
#include <hip/hip_runtime.h>
#include <hip/hip_bf16.h>
#include <math.h>

#define BATCH   16384
#define G_NUM   4096
#define NL      16
#define HD      256
#define INW     48
#define PADW    20   // padded row stride (floats): 80B, keeps float4 16B-aligned, breaks pow2 banks
#define OBSW    480

// Branch-free tanh: 1 - 2/(exp(2x)+1). exp overflow -> +1, underflow -> -1,
// so saturation is automatic; no NaN path. Uses raw v_rcp_f32 (1 ULP) via
// __builtin_amdgcn_rcpf — __frcp_rn would lower to the ~10-op correctly-
// rounded div sequence on AMD. |err| ~1e-6, threshold is 7.2e-3.
__device__ __forceinline__ float fast_tanh(float x) {
  float e = __expf(2.0f * x);
  return 1.0f - 2.0f * __builtin_amdgcn_rcpf(e + 1.0f);
}

// ---------------------------------------------------------------------------
// Quad-split GEMM: thread (jq=t>>2, sq=t&3) computes out[4sq..4sq+3][4jq..4jq+3].
// Per k: 1 ds_read_b128 (activation quad, 4 distinct addrs/wave, conflict-free)
//      + 1 coalesced global dwordx4 (weight quad) + 16 FMA.
// inT: transposed activations [K][PADW]; W: [K][256] global. tanh applied.
// Result written transposed to outT[(col)*PADW + row] as float4 per ji.
// ---------------------------------------------------------------------------
template<int K>
__device__ __forceinline__ void qgemm(const float* inT, const float* __restrict__ W,
                                      const float* __restrict__ bias,
                                      float* outT, int jq, int sq) {
  float acc[4][4];
  {
    const float4 bb = *(const float4*)(bias + 4 * jq);
    const float b4[4] = {bb.x, bb.y, bb.z, bb.w};
#pragma unroll
    for (int si = 0; si < 4; ++si)
#pragma unroll
      for (int ji = 0; ji < 4; ++ji) acc[si][ji] = b4[ji];
  }
  const float* arow = inT + 4 * sq;
  const float* wrow = W + 4 * jq;
#pragma unroll 4
  for (int k = 0; k < K; ++k) {
    const float4 av = *(const float4*)(arow + k * PADW);
    const float4 wv = *(const float4*)(wrow + (size_t)k * HD);
    const float a4[4] = {av.x, av.y, av.z, av.w};
    const float w4[4] = {wv.x, wv.y, wv.z, wv.w};
#pragma unroll
    for (int si = 0; si < 4; ++si)
#pragma unroll
      for (int ji = 0; ji < 4; ++ji) acc[si][ji] = fmaf(a4[si], w4[ji], acc[si][ji]);
  }
#pragma unroll
  for (int ji = 0; ji < 4; ++ji) {
    float4 o;
    o.x = fast_tanh(acc[0][ji]); o.y = fast_tanh(acc[1][ji]);
    o.z = fast_tanh(acc[2][ji]); o.w = fast_tanh(acc[3][ji]);
    *(float4*)(outT + (4 * jq + ji) * PADW + 4 * sq) = o;  // 16B aligned
  }
}

// Read column j (16 rows) of a transposed [256][PADW] LDS buffer.
__device__ __forceinline__ void read_col16(const float* buf, int j, float v[NL]) {
  const float4* p = (const float4*)(buf + j * PADW);
  float4 a0 = p[0], a1 = p[1], a2 = p[2], a3 = p[3];
  v[0]  = a0.x; v[1]  = a0.y; v[2]  = a0.z; v[3]  = a0.w;
  v[4]  = a1.x; v[5]  = a1.y; v[6]  = a1.z; v[7]  = a1.w;
  v[8]  = a2.x; v[9]  = a2.y; v[10] = a2.z; v[11] = a2.w;
  v[12] = a3.x; v[13] = a3.y; v[14] = a3.z; v[15] = a3.w;
}

// Block-wide reduction of 16 per-row partials over 256 threads.
// After return, red[w*16+s] holds per-wave sums; caller adds the 4 waves.
__device__ __forceinline__ void block_reduce16(float part[NL], float* red, int tid) {
#pragma unroll
  for (int d = 1; d < 64; d <<= 1) {
#pragma unroll
    for (int s = 0; s < NL; ++s) part[s] += __shfl_xor(part[s], d, 64);
  }
  __syncthreads();   // ensure any previous reads of red are done
  if ((tid & 63) == 0) {
    int w = tid >> 6;
#pragma unroll
    for (int s = 0; s < NL; ++s) red[w * NL + s] = part[s];
  }
  __syncthreads();
}

// ---------------------------------------------------------------------------
// Kernel 1: per batch row b — enc mlp2, val mlp2, 16-way attention -> ome[b]
// ---------------------------------------------------------------------------
__global__ __launch_bounds__(256) void k_main(
    const float* __restrict__ obs,
    const float* __restrict__ ew1, const float* __restrict__ eb1,
    const float* __restrict__ ew2, const float* __restrict__ eb2,
    const float* __restrict__ vw1, const float* __restrict__ vb1,
    const float* __restrict__ vw2, const float* __restrict__ vb2,
    float* __restrict__ ome_out) {
  __shared__ __align__(16) float xT[INW * PADW];
  __shared__ __align__(16) float bufA[HD * PADW];
  __shared__ __align__(16) float bufB[HD * PADW];
  __shared__ float red[4 * NL];

  const int j  = threadIdx.x;
  const int jq = j >> 2, sq = j & 3;
  const int b  = blockIdx.x;

  // ---- build x transposed: x[s] = [obs[(16b+s)%B, 0:32], obs[b, 96+16s : 112+16s]]
#pragma unroll
  for (int base = 0; base < 512; base += 256) {
    int e = base + j;
    int s = e >> 5;
    int c = e & 31;
    int row = ((b << 4) + s) & (BATCH - 1);
    xT[c * PADW + s] = obs[row * OBSW + c];
  }
  {
    int s = j >> 4, kk = j & 15;
    xT[(32 + kk) * PADW + s] = obs[b * OBSW + 96 + j];
  }
  __syncthreads();

  // ---- h1 = tanh(x @ enc_w1 + b1) -> bufA
  qgemm<INW>(xT, ew1, eb1, bufA, jq, sq);
  __syncthreads();

  // ---- emb = tanh(h1 @ enc_w2 + b2) -> bufB
  qgemm<HD>(bufA, ew2, eb2, bufB, jq, sq);
  __syncthreads();

  // ---- scores/softmax (per-column view)
  float ev[NL];
  read_col16(bufB, j, ev);
  float qsum = 0.f;
#pragma unroll
  for (int s = 0; s < NL; ++s) qsum += ev[s];
  float part[NL];
#pragma unroll
  for (int s = 0; s < NL; ++s) part[s] = qsum * ev[s];
  block_reduce16(part, red, j);

  float att[NL];
  {
    float sc[NL], mx = -1e30f;
#pragma unroll
    for (int s = 0; s < NL; ++s) {
      sc[s] = (red[s] + red[NL + s] + red[2 * NL + s] + red[3 * NL + s]) * (1.0f / 256.0f);
      mx = fmaxf(mx, sc[s]);
    }
    float se = 0.f;
#pragma unroll
    for (int s = 0; s < NL; ++s) { att[s] = expf(sc[s] - mx); se += att[s]; }
    float inv = 1.0f / se;
#pragma unroll
    for (int s = 0; s < NL; ++s) att[s] *= inv;
  }

  // ---- hv = tanh(emb @ val_w1 + b1) -> bufA
  // (bufA's h1 reads all completed before block_reduce16's internal syncs)
  qgemm<HD>(bufB, vw1, vb1, bufA, jq, sq);
  __syncthreads();

  // ---- v = tanh(hv @ val_w2 + b2) -> bufB (emb dead; all bufB reads done pre-sync)
  qgemm<HD>(bufA, vw2, vb2, bufB, jq, sq);
  __syncthreads();

  // ---- ome[b][j] = sum_s att[s] * v[s][j]
  float vv[NL];
  read_col16(bufB, j, vv);
  float omej = 0.f;
#pragma unroll
  for (int s = 0; s < NL; ++s) omej += att[s] * vv[s];
  ome_out[b * HD + j] = omej;
}

// ---------------------------------------------------------------------------
// Kernel 2: vals mlp2 + layernorm over 16 batch rows per block -> ov (ws)
// ---------------------------------------------------------------------------
__global__ __launch_bounds__(256) void k_vals(
    const float* __restrict__ ome,
    const float* __restrict__ w1, const float* __restrict__ b1,
    const float* __restrict__ w2, const float* __restrict__ b2,
    const float* __restrict__ lng, const float* __restrict__ lnb,
    float* __restrict__ ov) {
  __shared__ __align__(16) float inT[HD * PADW];
  __shared__ __align__(16) float midT[HD * PADW];
  __shared__ float red[4 * NL];

  const int j  = threadIdx.x;
  const int jq = j >> 2, sq = j & 3;
  const int r0 = blockIdx.x * NL;

  // load 16 rows of ome, transposed into LDS
#pragma unroll
  for (int i = 0; i < NL; ++i) {
    int e = i * 256 + j;
    int r = e >> 8, k = e & 255;
    inT[k * PADW + r] = ome[(r0 + r) * HD + k];
  }
  __syncthreads();

  qgemm<HD>(inT, w1, b1, midT, jq, sq);
  __syncthreads();

  // o0 -> inT region (inT reads all finished at previous sync)
  qgemm<HD>(midT, w2, b2, inT, jq, sq);
  __syncthreads();

  float o0[NL];
  read_col16(inT, j, o0);

  // layernorm per row s over the 256 columns
  float part[NL];
#pragma unroll
  for (int s = 0; s < NL; ++s) part[s] = o0[s];
  block_reduce16(part, red, j);
  float mu[NL];
#pragma unroll
  for (int s = 0; s < NL; ++s)
    mu[s] = (red[s] + red[NL + s] + red[2 * NL + s] + red[3 * NL + s]) * (1.0f / 256.0f);

#pragma unroll
  for (int s = 0; s < NL; ++s) { float d = o0[s] - mu[s]; part[s] = d * d; }
  block_reduce16(part, red, j);

  float gv = lng[j], bv = lnb[j];
#pragma unroll
  for (int s = 0; s < NL; ++s) {
    float var = (red[s] + red[NL + s] + red[2 * NL + s] + red[3 * NL + s]) * (1.0f / 256.0f);
    float y = (o0[s] - mu[s]) * rsqrtf(var + 1e-6f) * gv + bv;
    ov[(r0 + s) * HD + j] = y;
  }
}

// ---------------------------------------------------------------------------
// Kernel 3: group attention (G=4096, P=4, 8 heads x 32) + tile x4 output
// ---------------------------------------------------------------------------
__global__ __launch_bounds__(256) void k_group(
    const float* __restrict__ ome,
    const float* __restrict__ ov,
    float* __restrict__ out) {
  const int g = blockIdx.x;
  const int j = threadIdx.x;   // j = h*32 + a

  float m[4], o[4];
#pragma unroll
  for (int p = 0; p < 4; ++p) {
    m[p] = ome[(g * 4 + p) * HD + j];
    o[p] = ov[(g * 4 + p) * HD + j];
  }
  float qv = (m[0] + m[1] + m[2] + m[3]) * 0.25f * 0.17677669529663687f;  // mean/4 / sqrt(32)
  float sc[4];
#pragma unroll
  for (int p = 0; p < 4; ++p) {
    float t = qv * m[p];
#pragma unroll
    for (int d = 1; d < 32; d <<= 1) t += __shfl_xor(t, d, 64);  // reduce within 32-lane head
    sc[p] = t;
  }
  float mx = fmaxf(fmaxf(sc[0], sc[1]), fmaxf(sc[2], sc[3]));
  float e[4], se = 0.f;
#pragma unroll
  for (int p = 0; p < 4; ++p) { e[p] = expf(sc[p] - mx); se += e[p]; }
  float inv = 1.0f / se;
  float r = 0.f;
#pragma unroll
  for (int p = 0; p < 4; ++p) r += e[p] * inv * o[p];

#pragma unroll
  for (int rep = 0; rep < 4; ++rep) out[(rep * G_NUM + g) * HD + j] = r;
}

// ---------------------------------------------------------------------------
extern "C" void kernel_launch(void* const* d_in, const int* in_sizes, int n_in,
                              void* d_out, int out_size, void* d_ws, size_t ws_size,
                              hipStream_t stream) {
  const float* obs = (const float*)d_in[0];
  const float* ew1 = (const float*)d_in[1];
  const float* eb1 = (const float*)d_in[2];
  const float* ew2 = (const float*)d_in[3];
  const float* eb2 = (const float*)d_in[4];
  const float* vw1 = (const float*)d_in[5];
  const float* vb1 = (const float*)d_in[6];
  const float* vw2 = (const float*)d_in[7];
  const float* vb2 = (const float*)d_in[8];
  const float* sw1 = (const float*)d_in[9];
  const float* sb1 = (const float*)d_in[10];
  const float* sw2 = (const float*)d_in[11];
  const float* sb2 = (const float*)d_in[12];
  const float* lng = (const float*)d_in[13];
  const float* lnb = (const float*)d_in[14];

  float* out = (float*)d_out;
  float* ome = out + (size_t)BATCH * HD;  // output 2 region, also reused as input below
  float* ov  = (float*)d_ws;              // scratch (16 MB)

  k_main<<<BATCH, 256, 0, stream>>>(obs, ew1, eb1, ew2, eb2, vw1, vb1, vw2, vb2, ome);
  k_vals<<<BATCH / NL, 256, 0, stream>>>(ome, sw1, sb1, sw2, sb2, lng, lnb, ov);
  k_group<<<G_NUM, 256, 0, stream>>>(ome, ov, out);
}

// Round 8
// 1867.818 us; speedup vs baseline: 1.0137x; 1.0137x over previous
//
#include <hip/hip_runtime.h>
#include <hip/hip_bf16.h>
#include <math.h>

#define BATCH   16384
#define G_NUM   4096
#define NL      16
#define HD      256
#define INW     48
#define PADW    20   // padded row stride (floats): 80B, keeps float4 16B-aligned
#define OBSW    480

// Branch-free tanh: 1 - 2/(exp(2x)+1). exp overflow -> +1, underflow -> -1,
// saturation automatic; no NaN path. Raw v_rcp_f32 via __builtin_amdgcn_rcpf.
__device__ __forceinline__ float fast_tanh(float x) {
  float e = __expf(2.0f * x);
  return 1.0f - 2.0f * __builtin_amdgcn_rcpf(e + 1.0f);
}

// ---------------------------------------------------------------------------
// Quad-split GEMM, read phase only: thread (jq,sq) accumulates the 4x4 tile
// out[4sq..4sq+3][4jq..4jq+3] into registers. Caller barriers, then writes
// via write_tile_tanh — allowing input and output to share ONE LDS buffer.
// Per k: 1 ds_read_b128 (broadcast quad) + 1 coalesced global dwordx4 + 16 FMA.
// ---------------------------------------------------------------------------
template<int K>
__device__ __forceinline__ void qgemm_read(const float* inT, const float* __restrict__ W,
                                           const float* __restrict__ bias,
                                           int jq, int sq, float acc[4][4]) {
  {
    const float4 bb = *(const float4*)(bias + 4 * jq);
    const float b4[4] = {bb.x, bb.y, bb.z, bb.w};
#pragma unroll
    for (int si = 0; si < 4; ++si)
#pragma unroll
      for (int ji = 0; ji < 4; ++ji) acc[si][ji] = b4[ji];
  }
  const float* arow = inT + 4 * sq;
  const float* wrow = W + 4 * jq;
#pragma unroll 4
  for (int k = 0; k < K; ++k) {
    const float4 av = *(const float4*)(arow + k * PADW);
    const float4 wv = *(const float4*)(wrow + (size_t)k * HD);
    const float a4[4] = {av.x, av.y, av.z, av.w};
    const float w4[4] = {wv.x, wv.y, wv.z, wv.w};
#pragma unroll
    for (int si = 0; si < 4; ++si)
#pragma unroll
      for (int ji = 0; ji < 4; ++ji) acc[si][ji] = fmaf(a4[si], w4[ji], acc[si][ji]);
  }
}

// Write phase: tanh + store the 4x4 tile transposed ([col][row], float4 rows).
__device__ __forceinline__ void write_tile_tanh(float* outT, int jq, int sq,
                                                const float acc[4][4]) {
#pragma unroll
  for (int ji = 0; ji < 4; ++ji) {
    float4 o;
    o.x = fast_tanh(acc[0][ji]); o.y = fast_tanh(acc[1][ji]);
    o.z = fast_tanh(acc[2][ji]); o.w = fast_tanh(acc[3][ji]);
    *(float4*)(outT + (4 * jq + ji) * PADW + 4 * sq) = o;  // 16B aligned
  }
}

// Read column j (16 rows) of a transposed [256][PADW] LDS buffer.
__device__ __forceinline__ void read_col16(const float* buf, int j, float v[NL]) {
  const float4* p = (const float4*)(buf + j * PADW);
  float4 a0 = p[0], a1 = p[1], a2 = p[2], a3 = p[3];
  v[0]  = a0.x; v[1]  = a0.y; v[2]  = a0.z; v[3]  = a0.w;
  v[4]  = a1.x; v[5]  = a1.y; v[6]  = a1.z; v[7]  = a1.w;
  v[8]  = a2.x; v[9]  = a2.y; v[10] = a2.z; v[11] = a2.w;
  v[12] = a3.x; v[13] = a3.y; v[14] = a3.z; v[15] = a3.w;
}

// Block-wide reduction of 16 per-row partials over 256 threads.
__device__ __forceinline__ void block_reduce16(float part[NL], float* red, int tid) {
#pragma unroll
  for (int d = 1; d < 64; d <<= 1) {
#pragma unroll
    for (int s = 0; s < NL; ++s) part[s] += __shfl_xor(part[s], d, 64);
  }
  __syncthreads();
  if ((tid & 63) == 0) {
    int w = tid >> 6;
#pragma unroll
    for (int s = 0; s < NL; ++s) red[w * NL + s] = part[s];
  }
  __syncthreads();
}

// ---------------------------------------------------------------------------
// Kernel 1: per batch row b — enc mlp2, val mlp2, 16-way attention -> ome[b]
// Single 20.7KB LDS buffer (read-phase/write-phase split) -> up to 7 blocks/CU;
// launch_bounds(...,8) targets <=64 VGPR for 8 waves/EU.
// ---------------------------------------------------------------------------
__global__ __launch_bounds__(256, 8) void k_main(
    const float* __restrict__ obs,
    const float* __restrict__ ew1, const float* __restrict__ eb1,
    const float* __restrict__ ew2, const float* __restrict__ eb2,
    const float* __restrict__ vw1, const float* __restrict__ vb1,
    const float* __restrict__ vw2, const float* __restrict__ vb2,
    float* __restrict__ ome_out) {
  __shared__ __align__(16) float buf[HD * PADW];
  __shared__ float red[4 * NL];

  const int j  = threadIdx.x;
  const int jq = j >> 2, sq = j & 3;
  const int b  = blockIdx.x;

  // ---- x (transposed) into buf rows 0..47:
  // x[s] = [obs[(16b+s)%B, 0:32], obs[b, 96+16s : 112+16s]]
#pragma unroll
  for (int base = 0; base < 512; base += 256) {
    int e = base + j;
    int s = e >> 5;
    int c = e & 31;
    int row = ((b << 4) + s) & (BATCH - 1);
    buf[c * PADW + s] = obs[row * OBSW + c];
  }
  {
    int s = j >> 4, kk = j & 15;
    buf[(32 + kk) * PADW + s] = obs[b * OBSW + 96 + j];
  }
  __syncthreads();

  float acc[4][4];

  // ---- h1 = tanh(x @ enc_w1 + b1)
  qgemm_read<INW>(buf, ew1, eb1, jq, sq, acc);
  __syncthreads();                 // all x reads done
  write_tile_tanh(buf, jq, sq, acc);
  __syncthreads();

  // ---- emb = tanh(h1 @ enc_w2 + b2)
  qgemm_read<HD>(buf, ew2, eb2, jq, sq, acc);
  __syncthreads();                 // all h1 reads done
  write_tile_tanh(buf, jq, sq, acc);
  __syncthreads();

  // ---- scores/softmax from emb (in buf)
  float ev[NL];
  read_col16(buf, j, ev);
  float qsum = 0.f;
#pragma unroll
  for (int s = 0; s < NL; ++s) qsum += ev[s];
  float part[NL];
#pragma unroll
  for (int s = 0; s < NL; ++s) part[s] = qsum * ev[s];
  block_reduce16(part, red, j);

  float att[NL];
  {
    float sc[NL], mx = -1e30f;
#pragma unroll
    for (int s = 0; s < NL; ++s) {
      sc[s] = (red[s] + red[NL + s] + red[2 * NL + s] + red[3 * NL + s]) * (1.0f / 256.0f);
      mx = fmaxf(mx, sc[s]);
    }
    float se = 0.f;
#pragma unroll
    for (int s = 0; s < NL; ++s) { att[s] = expf(sc[s] - mx); se += att[s]; }
    float inv = 1.0f / se;
#pragma unroll
    for (int s = 0; s < NL; ++s) att[s] *= inv;
  }

  // ---- hv = tanh(emb @ val_w1 + b1)   (emb still in buf)
  qgemm_read<HD>(buf, vw1, vb1, jq, sq, acc);
  __syncthreads();                 // all emb reads done
  write_tile_tanh(buf, jq, sq, acc);
  __syncthreads();

  // ---- v = tanh(hv @ val_w2 + b2)
  qgemm_read<HD>(buf, vw2, vb2, jq, sq, acc);
  __syncthreads();                 // all hv reads done
  write_tile_tanh(buf, jq, sq, acc);
  __syncthreads();

  // ---- ome[b][j] = sum_s att[s] * v[s][j]
  float vv[NL];
  read_col16(buf, j, vv);
  float omej = 0.f;
#pragma unroll
  for (int s = 0; s < NL; ++s) omej += att[s] * vv[s];
  ome_out[b * HD + j] = omej;
}

// ---------------------------------------------------------------------------
// Kernel 2: vals mlp2 + layernorm over 16 batch rows per block -> ov (ws)
// ---------------------------------------------------------------------------
__global__ __launch_bounds__(256, 8) void k_vals(
    const float* __restrict__ ome,
    const float* __restrict__ w1, const float* __restrict__ b1,
    const float* __restrict__ w2, const float* __restrict__ b2,
    const float* __restrict__ lng, const float* __restrict__ lnb,
    float* __restrict__ ov) {
  __shared__ __align__(16) float buf[HD * PADW];
  __shared__ float red[4 * NL];

  const int j  = threadIdx.x;
  const int jq = j >> 2, sq = j & 3;
  const int r0 = blockIdx.x * NL;

  // load 16 rows of ome, transposed into buf
#pragma unroll
  for (int i = 0; i < NL; ++i) {
    int e = i * 256 + j;
    int r = e >> 8, k = e & 255;
    buf[k * PADW + r] = ome[(r0 + r) * HD + k];
  }
  __syncthreads();

  float acc[4][4];
  qgemm_read<HD>(buf, w1, b1, jq, sq, acc);
  __syncthreads();
  write_tile_tanh(buf, jq, sq, acc);
  __syncthreads();

  qgemm_read<HD>(buf, w2, b2, jq, sq, acc);
  __syncthreads();
  write_tile_tanh(buf, jq, sq, acc);
  __syncthreads();

  float o0[NL];
  read_col16(buf, j, o0);

  // layernorm per row s over the 256 columns
  float part[NL];
#pragma unroll
  for (int s = 0; s < NL; ++s) part[s] = o0[s];
  block_reduce16(part, red, j);
  float mu[NL];
#pragma unroll
  for (int s = 0; s < NL; ++s)
    mu[s] = (red[s] + red[NL + s] + red[2 * NL + s] + red[3 * NL + s]) * (1.0f / 256.0f);

#pragma unroll
  for (int s = 0; s < NL; ++s) { float d = o0[s] - mu[s]; part[s] = d * d; }
  block_reduce16(part, red, j);

  float gv = lng[j], bv = lnb[j];
#pragma unroll
  for (int s = 0; s < NL; ++s) {
    float var = (red[s] + red[NL + s] + red[2 * NL + s] + red[3 * NL + s]) * (1.0f / 256.0f);
    float y = (o0[s] - mu[s]) * rsqrtf(var + 1e-6f) * gv + bv;
    ov[(r0 + s) * HD + j] = y;
  }
}

// ---------------------------------------------------------------------------
// Kernel 3: group attention (G=4096, P=4, 8 heads x 32) + tile x4 output
// ---------------------------------------------------------------------------
__global__ __launch_bounds__(256) void k_group(
    const float* __restrict__ ome,
    const float* __restrict__ ov,
    float* __restrict__ out) {
  const int g = blockIdx.x;
  const int j = threadIdx.x;   // j = h*32 + a

  float m[4], o[4];
#pragma unroll
  for (int p = 0; p < 4; ++p) {
    m[p] = ome[(g * 4 + p) * HD + j];
    o[p] = ov[(g * 4 + p) * HD + j];
  }
  float qv = (m[0] + m[1] + m[2] + m[3]) * 0.25f * 0.17677669529663687f;  // mean/4 / sqrt(32)
  float sc[4];
#pragma unroll
  for (int p = 0; p < 4; ++p) {
    float t = qv * m[p];
#pragma unroll
    for (int d = 1; d < 32; d <<= 1) t += __shfl_xor(t, d, 64);  // reduce within 32-lane head
    sc[p] = t;
  }
  float mx = fmaxf(fmaxf(sc[0], sc[1]), fmaxf(sc[2], sc[3]));
  float e[4], se = 0.f;
#pragma unroll
  for (int p = 0; p < 4; ++p) { e[p] = expf(sc[p] - mx); se += e[p]; }
  float inv = 1.0f / se;
  float r = 0.f;
#pragma unroll
  for (int p = 0; p < 4; ++p) r += e[p] * inv * o[p];

#pragma unroll
  for (int rep = 0; rep < 4; ++rep) out[(rep * G_NUM + g) * HD + j] = r;
}

// ---------------------------------------------------------------------------
extern "C" void kernel_launch(void* const* d_in, const int* in_sizes, int n_in,
                              void* d_out, int out_size, void* d_ws, size_t ws_size,
                              hipStream_t stream) {
  const float* obs = (const float*)d_in[0];
  const float* ew1 = (const float*)d_in[1];
  const float* eb1 = (const float*)d_in[2];
  const float* ew2 = (const float*)d_in[3];
  const float* eb2 = (const float*)d_in[4];
  const float* vw1 = (const float*)d_in[5];
  const float* vb1 = (const float*)d_in[6];
  const float* vw2 = (const float*)d_in[7];
  const float* vb2 = (const float*)d_in[8];
  const float* sw1 = (const float*)d_in[9];
  const float* sb1 = (const float*)d_in[10];
  const float* sw2 = (const float*)d_in[11];
  const float* sb2 = (const float*)d_in[12];
  const float* lng = (const float*)d_in[13];
  const float* lnb = (const float*)d_in[14];

  float* out = (float*)d_out;
  float* ome = out + (size_t)BATCH * HD;  // output 2 region, also reused as input below
  float* ov  = (float*)d_ws;              // scratch (16 MB)

  k_main<<<BATCH, 256, 0, stream>>>(obs, ew1, eb1, ew2, eb2, vw1, vb1, vw2, vb2, ome);
  k_vals<<<BATCH / NL, 256, 0, stream>>>(ome, sw1, sb1, sw2, sb2, lng, lnb, ov);
  k_group<<<G_NUM, 256, 0, stream>>>(ome, ov, out);
}

// Round 10
// 596.333 us; speedup vs baseline: 3.1749x; 3.1322x over previous
//
#include <hip/hip_runtime.h>
#include <hip/hip_bf16.h>
#include <math.h>

#define BATCH   16384
#define G_NUM   4096
#define NL      16
#define HD      256
#define OBSW    480
#define LDA     264      // ushort stride of activation LDS rows (528B: 16B-aligned)

using bf16x8 = __attribute__((ext_vector_type(8))) short;   // 8 bf16 = 4 VGPRs
using f32x4  = __attribute__((ext_vector_type(4))) float;

// Packed-weight element offsets (ushort units) inside wpk:
// per matrix: [tile(16)][ks][lane(64)][8] bf16, hi then lo.
#define E1H 0
#define E1L 16384
#define E2H 32768
#define E2L 98304
#define V1H 163840
#define V1L 229376
#define V2H 294912
#define V2L 360448
#define PACK_ELEMS 425984  // 832 KB

__device__ __forceinline__ float fast_tanh(float x) {
  float e = __expf(2.0f * x);
  return 1.0f - 2.0f * __builtin_amdgcn_rcpf(e + 1.0f);
}

__device__ __forceinline__ unsigned short f32_to_bf16(float x) {
  unsigned u = __float_as_uint(x);
  return (unsigned short)((u + 0x7fffu + ((u >> 16) & 1u)) >> 16);
}
__device__ __forceinline__ float bf16_to_f32(unsigned short h) {
  return __uint_as_float(((unsigned)h) << 16);
}
__device__ __forceinline__ void split_bf16(float x, unsigned short& hi, unsigned short& lo) {
  hi = f32_to_bf16(x);
  lo = f32_to_bf16(x - bf16_to_f32(hi));
}

// ---------------------------------------------------------------------------
// k_pack: repack fp32 weights [K][256] into MFMA B-fragment order, split hi/lo.
// Fragment: lane l holds B[k0 + 8*(l>>4) + i][c0 + (l&15)], i=0..7 contiguous.
// ---------------------------------------------------------------------------
__global__ void k_pack(const float* __restrict__ ew1, const float* __restrict__ ew2,
                       const float* __restrict__ vw1, const float* __restrict__ vw2,
                       unsigned short* __restrict__ wpk) {
  int bid = blockIdx.x, lane = threadIdx.x;
  const float* W; int KS, K, baseh, basel;
  if (bid < 32)       { W = ew1; KS = 2; K = 48;  baseh = E1H; basel = E1L; }
  else if (bid < 160) { W = ew2; KS = 8; K = 256; baseh = E2H; basel = E2L; bid -= 32; }
  else if (bid < 288) { W = vw1; KS = 8; K = 256; baseh = V1H; basel = V1L; bid -= 160; }
  else                { W = vw2; KS = 8; K = 256; baseh = V2H; basel = V2L; bid -= 288; }
  int t = bid & 15, ks = bid >> 4;
  int g = lane >> 4, c = t * 16 + (lane & 15);
  unsigned short hv[8], lv[8];
#pragma unroll
  for (int i = 0; i < 8; ++i) {
    int k = ks * 32 + g * 8 + i;
    float v = (k < K) ? W[k * HD + c] : 0.f;
    split_bf16(v, hv[i], lv[i]);
  }
  size_t off = ((size_t)(t * KS + ks) * 64 + lane) * 8;
#pragma unroll
  for (int i = 0; i < 8; ++i) { wpk[baseh + off + i] = hv[i]; wpk[basel + off + i] = lv[i]; }
}

// ---------------------------------------------------------------------------
// 3-term split-bf16 MFMA GEMM layer: A[64][K] (LDS, split) x W[K][256] (packed).
// Wave w owns cols [64w,64w+64): acc[mt][nt] = 16x16 D-tiles.
// ---------------------------------------------------------------------------
template<int KS>
__device__ __forceinline__ void mfma_layer(const unsigned short* Ahi, const unsigned short* Alo,
                                           const unsigned short* __restrict__ Bhi,
                                           const unsigned short* __restrict__ Blo,
                                           const float* __restrict__ bias,
                                           int w, int lane, f32x4 acc[4][4]) {
  const int m16 = lane & 15, g = lane >> 4;
#pragma unroll
  for (int nt = 0; nt < 4; ++nt) {
    float b = bias[(4 * w + nt) * 16 + m16];   // D col = lane&15
#pragma unroll
    for (int mt = 0; mt < 4; ++mt) { acc[mt][nt][0] = b; acc[mt][nt][1] = b; acc[mt][nt][2] = b; acc[mt][nt][3] = b; }
  }
#pragma unroll 2
  for (int ks = 0; ks < KS; ++ks) {
    bf16x8 ah[4], al[4];
#pragma unroll
    for (int mt = 0; mt < 4; ++mt) {
      int off = (16 * mt + m16) * LDA + ks * 32 + 8 * g;
      ah[mt] = *(const bf16x8*)(Ahi + off);
      al[mt] = *(const bf16x8*)(Alo + off);
    }
#pragma unroll
    for (int nt = 0; nt < 4; ++nt) {
      size_t foff = ((size_t)((4 * w + nt) * KS + ks) * 64 + lane) * 8;
      bf16x8 bh = *(const bf16x8*)(Bhi + foff);
      bf16x8 bl = *(const bf16x8*)(Blo + foff);
#pragma unroll
      for (int mt = 0; mt < 4; ++mt) {
        acc[mt][nt] = __builtin_amdgcn_mfma_f32_16x16x32_bf16(ah[mt], bh, acc[mt][nt], 0, 0, 0);
        acc[mt][nt] = __builtin_amdgcn_mfma_f32_16x16x32_bf16(ah[mt], bl, acc[mt][nt], 0, 0, 0);
        acc[mt][nt] = __builtin_amdgcn_mfma_f32_16x16x32_bf16(al[mt], bh, acc[mt][nt], 0, 0, 0);
      }
    }
  }
}

// tanh + split + store C-frags back to the activation LDS (row-major [64][LDA]).
__device__ __forceinline__ void store_acts(f32x4 acc[4][4], unsigned short* Ahi,
                                           unsigned short* Alo, int w, int lane) {
  const int m16 = lane & 15, g = lane >> 4;
#pragma unroll
  for (int mt = 0; mt < 4; ++mt)
#pragma unroll
    for (int nt = 0; nt < 4; ++nt) {
      int col = (4 * w + nt) * 16 + m16;
#pragma unroll
      for (int r = 0; r < 4; ++r) {
        int row = 16 * mt + 4 * g + r;
        unsigned short h, l;
        split_bf16(fast_tanh(acc[mt][nt][r]), h, l);
        Ahi[row * LDA + col] = h;
        Alo[row * LDA + col] = l;
      }
    }
}

// Block-wide reduction of 16 per-row partials over 256 threads.
__device__ __forceinline__ void block_reduce16(float part[NL], float* red, int tid) {
#pragma unroll
  for (int d = 1; d < 64; d <<= 1) {
#pragma unroll
    for (int s = 0; s < NL; ++s) part[s] += __shfl_xor(part[s], d, 64);
  }
  __syncthreads();
  if ((tid & 63) == 0) {
    int w = tid >> 6;
#pragma unroll
    for (int s = 0; s < NL; ++s) red[w * NL + s] = part[s];
  }
  __syncthreads();
}

// ---------------------------------------------------------------------------
// k_main: 4 batch rows per block (M=64). enc mlp2 -> softmax -> val mlp2 -> ome.
// ---------------------------------------------------------------------------
__global__ __launch_bounds__(256) void k_main(
    const float* __restrict__ obs,
    const float* __restrict__ eb1, const float* __restrict__ eb2,
    const float* __restrict__ vb1, const float* __restrict__ vb2,
    const unsigned short* __restrict__ wpk,
    float* __restrict__ ome_out) {
  __shared__ __align__(16) unsigned short Ahi[64 * LDA];
  __shared__ __align__(16) unsigned short Alo[64 * LDA];
  __shared__ float red[4 * NL];
  __shared__ float att_lds[4 * NL];

  const int tid = threadIdx.x;
  const int w = tid >> 6, lane = tid & 63;
  const int b = blockIdx.x;

  // ---- stage x split into A rows (k<48 real, 48..63 zero) ----
#pragma unroll
  for (int r = 0; r < 8; ++r) {           // self: 64 rows x 32 cols
    int e = r * 256 + tid, m = e >> 5, c = e & 31;
    int srow = (64 * b + m) & (BATCH - 1);
    unsigned short h, l; split_bf16(obs[srow * OBSW + c], h, l);
    Ahi[m * LDA + c] = h; Alo[m * LDA + c] = l;
  }
#pragma unroll
  for (int r = 0; r < 4; ++r) {           // obstacle: 64 rows x 16 cols
    int e = r * 256 + tid, m = e >> 4, kk = e & 15;
    float v = obs[(4 * b + (m >> 4)) * OBSW + 96 + 16 * (m & 15) + kk];
    unsigned short h, l; split_bf16(v, h, l);
    Ahi[m * LDA + 32 + kk] = h; Alo[m * LDA + 32 + kk] = l;
  }
#pragma unroll
  for (int r = 0; r < 4; ++r) {           // zero pad k in [48,64)
    int e = r * 256 + tid, m = e >> 4, kk = e & 15;
    Ahi[m * LDA + 48 + kk] = 0; Alo[m * LDA + 48 + kk] = 0;
  }
  __syncthreads();

  f32x4 acc[4][4];

  // h1 = tanh(x @ enc_w1 + b1)
  mfma_layer<2>(Ahi, Alo, wpk + E1H, wpk + E1L, eb1, w, lane, acc);
  __syncthreads();
  store_acts(acc, Ahi, Alo, w, lane);
  __syncthreads();

  // emb = tanh(h1 @ enc_w2 + b2)
  mfma_layer<8>(Ahi, Alo, wpk + E2H, wpk + E2L, eb2, w, lane, acc);
  __syncthreads();
  store_acts(acc, Ahi, Alo, w, lane);
  __syncthreads();

  // ---- softmax over s per batch row p (scores = (1/256) * sum_j q_j k_j) ----
  for (int p = 0; p < 4; ++p) {
    float ev[NL];
#pragma unroll
    for (int s = 0; s < NL; ++s) {
      int row = 16 * p + s;
      ev[s] = bf16_to_f32(Ahi[row * LDA + tid]) + bf16_to_f32(Alo[row * LDA + tid]);
    }
    float qsum = 0.f;
#pragma unroll
    for (int s = 0; s < NL; ++s) qsum += ev[s];
    float part[NL];
#pragma unroll
    for (int s = 0; s < NL; ++s) part[s] = qsum * ev[s];
    block_reduce16(part, red, tid);
    float sc[NL], mx = -1e30f;
#pragma unroll
    for (int s = 0; s < NL; ++s) {
      sc[s] = (red[s] + red[NL + s] + red[2 * NL + s] + red[3 * NL + s]) * (1.0f / 256.0f);
      mx = fmaxf(mx, sc[s]);
    }
    float se = 0.f, at[NL];
#pragma unroll
    for (int s = 0; s < NL; ++s) { at[s] = expf(sc[s] - mx); se += at[s]; }
    float inv = 1.0f / se;
    if (tid < NL) att_lds[p * NL + tid] = at[tid] * inv;
  }

  // hv = tanh(emb @ val_w1 + b1)   (reads emb from A; write after barrier)
  mfma_layer<8>(Ahi, Alo, wpk + V1H, wpk + V1L, vb1, w, lane, acc);
  __syncthreads();
  store_acts(acc, Ahi, Alo, w, lane);
  __syncthreads();

  // v = tanh(hv @ val_w2 + b2)
  mfma_layer<8>(Ahi, Alo, wpk + V2H, wpk + V2L, vb2, w, lane, acc);
  __syncthreads();
  store_acts(acc, Ahi, Alo, w, lane);
  __syncthreads();

  // ome[p][j] = sum_s att[p][s] * v[16p+s][j]
#pragma unroll
  for (int p = 0; p < 4; ++p) {
    float o = 0.f;
#pragma unroll
    for (int s = 0; s < NL; ++s) {
      int row = 16 * p + s;
      float vv = bf16_to_f32(Ahi[row * LDA + tid]) + bf16_to_f32(Alo[row * LDA + tid]);
      o += att_lds[p * NL + s] * vv;
    }
    ome_out[(size_t)(4 * b + p) * HD + tid] = o;
  }
}

// ---------------------------------------------------------------------------
// k_vals (unchanged from validated round-8 kernel): fp32 VALU mlp2 + layernorm
// ---------------------------------------------------------------------------
#define PADW 20
template<int K>
__device__ __forceinline__ void qgemm_read(const float* inT, const float* __restrict__ W,
                                           const float* __restrict__ bias,
                                           int jq, int sq, float acc[4][4]) {
  {
    const float4 bb = *(const float4*)(bias + 4 * jq);
    const float b4[4] = {bb.x, bb.y, bb.z, bb.w};
#pragma unroll
    for (int si = 0; si < 4; ++si)
#pragma unroll
      for (int ji = 0; ji < 4; ++ji) acc[si][ji] = b4[ji];
  }
  const float* arow = inT + 4 * sq;
  const float* wrow = W + 4 * jq;
#pragma unroll 4
  for (int k = 0; k < K; ++k) {
    const float4 av = *(const float4*)(arow + k * PADW);
    const float4 wv = *(const float4*)(wrow + (size_t)k * HD);
    const float a4[4] = {av.x, av.y, av.z, av.w};
    const float w4[4] = {wv.x, wv.y, wv.z, wv.w};
#pragma unroll
    for (int si = 0; si < 4; ++si)
#pragma unroll
      for (int ji = 0; ji < 4; ++ji) acc[si][ji] = fmaf(a4[si], w4[ji], acc[si][ji]);
  }
}
__device__ __forceinline__ void write_tile_tanh(float* outT, int jq, int sq,
                                                const float acc[4][4]) {
#pragma unroll
  for (int ji = 0; ji < 4; ++ji) {
    float4 o;
    o.x = fast_tanh(acc[0][ji]); o.y = fast_tanh(acc[1][ji]);
    o.z = fast_tanh(acc[2][ji]); o.w = fast_tanh(acc[3][ji]);
    *(float4*)(outT + (4 * jq + ji) * PADW + 4 * sq) = o;
  }
}
__device__ __forceinline__ void read_col16(const float* buf, int j, float v[NL]) {
  const float4* p = (const float4*)(buf + j * PADW);
  float4 a0 = p[0], a1 = p[1], a2 = p[2], a3 = p[3];
  v[0]=a0.x; v[1]=a0.y; v[2]=a0.z; v[3]=a0.w; v[4]=a1.x; v[5]=a1.y; v[6]=a1.z; v[7]=a1.w;
  v[8]=a2.x; v[9]=a2.y; v[10]=a2.z; v[11]=a2.w; v[12]=a3.x; v[13]=a3.y; v[14]=a3.z; v[15]=a3.w;
}
__global__ __launch_bounds__(256, 8) void k_vals(
    const float* __restrict__ ome,
    const float* __restrict__ w1, const float* __restrict__ b1,
    const float* __restrict__ w2, const float* __restrict__ b2,
    const float* __restrict__ lng, const float* __restrict__ lnb,
    float* __restrict__ ov) {
  __shared__ __align__(16) float buf[HD * PADW];
  __shared__ float red[4 * NL];
  const int j = threadIdx.x, jq = j >> 2, sq = j & 3;
  const int r0 = blockIdx.x * NL;
#pragma unroll
  for (int i = 0; i < NL; ++i) {
    int e = i * 256 + j, r = e >> 8, k = e & 255;
    buf[k * PADW + r] = ome[(size_t)(r0 + r) * HD + k];
  }
  __syncthreads();
  float acc[4][4];
  qgemm_read<HD>(buf, w1, b1, jq, sq, acc);
  __syncthreads();
  write_tile_tanh(buf, jq, sq, acc);
  __syncthreads();
  qgemm_read<HD>(buf, w2, b2, jq, sq, acc);
  __syncthreads();
  write_tile_tanh(buf, jq, sq, acc);
  __syncthreads();
  float o0[NL];
  read_col16(buf, j, o0);
  float part[NL];
#pragma unroll
  for (int s = 0; s < NL; ++s) part[s] = o0[s];
  block_reduce16(part, red, j);
  float mu[NL];
#pragma unroll
  for (int s = 0; s < NL; ++s)
    mu[s] = (red[s] + red[NL + s] + red[2 * NL + s] + red[3 * NL + s]) * (1.0f / 256.0f);
#pragma unroll
  for (int s = 0; s < NL; ++s) { float d = o0[s] - mu[s]; part[s] = d * d; }
  block_reduce16(part, red, j);
  float gv = lng[j], bv = lnb[j];
#pragma unroll
  for (int s = 0; s < NL; ++s) {
    float var = (red[s] + red[NL + s] + red[2 * NL + s] + red[3 * NL + s]) * (1.0f / 256.0f);
    ov[(size_t)(r0 + s) * HD + j] = (o0[s] - mu[s]) * rsqrtf(var + 1e-6f) * gv + bv;
  }
}

// ---------------------------------------------------------------------------
// k_group (unchanged): group attention + tile x4 output
// ---------------------------------------------------------------------------
__global__ __launch_bounds__(256) void k_group(
    const float* __restrict__ ome,
    const float* __restrict__ ov,
    float* __restrict__ out) {
  const int g = blockIdx.x, j = threadIdx.x;
  float m[4], o[4];
#pragma unroll
  for (int p = 0; p < 4; ++p) {
    m[p] = ome[(size_t)(g * 4 + p) * HD + j];
    o[p] = ov[(size_t)(g * 4 + p) * HD + j];
  }
  float qv = (m[0] + m[1] + m[2] + m[3]) * 0.25f * 0.17677669529663687f;
  float sc[4];
#pragma unroll
  for (int p = 0; p < 4; ++p) {
    float t = qv * m[p];
#pragma unroll
    for (int d = 1; d < 32; d <<= 1) t += __shfl_xor(t, d, 64);
    sc[p] = t;
  }
  float mx = fmaxf(fmaxf(sc[0], sc[1]), fmaxf(sc[2], sc[3]));
  float e[4], se = 0.f;
#pragma unroll
  for (int p = 0; p < 4; ++p) { e[p] = expf(sc[p] - mx); se += e[p]; }
  float inv = 1.0f / se, r = 0.f;
#pragma unroll
  for (int p = 0; p < 4; ++p) r += e[p] * inv * o[p];
#pragma unroll
  for (int rep = 0; rep < 4; ++rep) out[(size_t)(rep * G_NUM + g) * HD + j] = r;
}

// ---------------------------------------------------------------------------
extern "C" void kernel_launch(void* const* d_in, const int* in_sizes, int n_in,
                              void* d_out, int out_size, void* d_ws, size_t ws_size,
                              hipStream_t stream) {
  const float* obs = (const float*)d_in[0];
  const float* ew1 = (const float*)d_in[1];
  const float* eb1 = (const float*)d_in[2];
  const float* ew2 = (const float*)d_in[3];
  const float* eb2 = (const float*)d_in[4];
  const float* vw1 = (const float*)d_in[5];
  const float* vb1 = (const float*)d_in[6];
  const float* vw2 = (const float*)d_in[7];
  const float* vb2 = (const float*)d_in[8];
  const float* sw1 = (const float*)d_in[9];
  const float* sb1 = (const float*)d_in[10];
  const float* sw2 = (const float*)d_in[11];
  const float* sb2 = (const float*)d_in[12];
  const float* lng = (const float*)d_in[13];
  const float* lnb = (const float*)d_in[14];

  float* out = (float*)d_out;
  float* ome = out + (size_t)BATCH * HD;   // output 2 region (also consumed below)
  float* ov  = (float*)d_ws;               // 16.78 MB

  const size_t OV_BYTES = (size_t)BATCH * HD * 4;
  const size_t PACK_BYTES = (size_t)PACK_ELEMS * 2;
  unsigned short* wpk;
  if (ws_size >= OV_BYTES + PACK_BYTES)
    wpk = (unsigned short*)((char*)d_ws + OV_BYTES);
  else
    wpk = (unsigned short*)d_out;  // first 832 KB of out; fully overwritten by k_group later

  k_pack<<<416, 64, 0, stream>>>(ew1, ew2, vw1, vw2, wpk);
  k_main<<<G_NUM, 256, 0, stream>>>(obs, eb1, eb2, vb1, vb2, wpk, ome);
  k_vals<<<BATCH / NL, 256, 0, stream>>>(ome, sw1, sb1, sw2, sb2, lng, lnb, ov);
  k_group<<<G_NUM, 256, 0, stream>>>(ome, ov, out);
}

// Round 11
// 510.279 us; speedup vs baseline: 3.7104x; 1.1686x over previous
//
#include <hip/hip_runtime.h>
#include <hip/hip_bf16.h>
#include <math.h>

#define BATCH   16384
#define G_NUM   4096
#define NL      16
#define HD      256
#define OBSW    480
#define LDA     264      // ushort stride of activation LDS rows (528B: 16B-aligned)

using bf16x8 = __attribute__((ext_vector_type(8))) short;   // 8 bf16 = 4 VGPRs
using f32x4  = __attribute__((ext_vector_type(4))) float;

// Packed-weight element offsets (ushort units) inside wpk:
// per matrix: [tile(16)][ks][lane(64)][8] bf16, hi then lo.
#define E1H 0
#define E1L 16384
#define E2H 32768
#define E2L 98304
#define V1H 163840
#define V1L 229376
#define V2H 294912
#define V2L 360448
#define PACK_ELEMS 425984  // 832 KB

__device__ __forceinline__ float fast_tanh(float x) {
  float e = __expf(2.0f * x);
  return 1.0f - 2.0f * __builtin_amdgcn_rcpf(e + 1.0f);
}

__device__ __forceinline__ unsigned short f32_to_bf16(float x) {
  unsigned u = __float_as_uint(x);
  return (unsigned short)((u + 0x7fffu + ((u >> 16) & 1u)) >> 16);
}
__device__ __forceinline__ float bf16_to_f32(unsigned short h) {
  return __uint_as_float(((unsigned)h) << 16);
}
__device__ __forceinline__ void split_bf16(float x, unsigned short& hi, unsigned short& lo) {
  hi = f32_to_bf16(x);
  lo = f32_to_bf16(x - bf16_to_f32(hi));
}

// ---------------------------------------------------------------------------
// k_pack: repack fp32 weights [K][256] into MFMA B-fragment order, split hi/lo.
// Fragment: lane l holds B[k0 + 8*(l>>4) + i][c0 + (l&15)], i=0..7 contiguous.
// ---------------------------------------------------------------------------
__global__ void k_pack(const float* __restrict__ ew1, const float* __restrict__ ew2,
                       const float* __restrict__ vw1, const float* __restrict__ vw2,
                       unsigned short* __restrict__ wpk) {
  int bid = blockIdx.x, lane = threadIdx.x;
  const float* W; int KS, K, baseh, basel;
  if (bid < 32)       { W = ew1; KS = 2; K = 48;  baseh = E1H; basel = E1L; }
  else if (bid < 160) { W = ew2; KS = 8; K = 256; baseh = E2H; basel = E2L; bid -= 32; }
  else if (bid < 288) { W = vw1; KS = 8; K = 256; baseh = V1H; basel = V1L; bid -= 160; }
  else                { W = vw2; KS = 8; K = 256; baseh = V2H; basel = V2L; bid -= 288; }
  int t = bid & 15, ks = bid >> 4;
  int g = lane >> 4, c = t * 16 + (lane & 15);
  unsigned short hv[8], lv[8];
#pragma unroll
  for (int i = 0; i < 8; ++i) {
    int k = ks * 32 + g * 8 + i;
    float v = (k < K) ? W[k * HD + c] : 0.f;
    split_bf16(v, hv[i], lv[i]);
  }
  size_t off = ((size_t)(t * KS + ks) * 64 + lane) * 8;
#pragma unroll
  for (int i = 0; i < 8; ++i) { wpk[baseh + off + i] = hv[i]; wpk[basel + off + i] = lv[i]; }
}

// ---------------------------------------------------------------------------
// 3-term split-bf16 MFMA layer, 8-wave version: wave w owns cols 32w..32w+31
// (nt2 in {0,1}, global nt = 2w+nt2). acc[mt][nt2] over 64 rows.
// ---------------------------------------------------------------------------
template<int KS>
__device__ __forceinline__ void mfma_layer8(const unsigned short* Ahi, const unsigned short* Alo,
                                            const unsigned short* __restrict__ Bhi,
                                            const unsigned short* __restrict__ Blo,
                                            const float* __restrict__ bias,
                                            int w, int lane, f32x4 acc[4][2]) {
  const int m16 = lane & 15, g = lane >> 4;
#pragma unroll
  for (int nt2 = 0; nt2 < 2; ++nt2) {
    float b = bias[(2 * w + nt2) * 16 + m16];   // D col = lane&15
#pragma unroll
    for (int mt = 0; mt < 4; ++mt) {
      acc[mt][nt2][0] = b; acc[mt][nt2][1] = b; acc[mt][nt2][2] = b; acc[mt][nt2][3] = b;
    }
  }
#pragma unroll 2
  for (int ks = 0; ks < KS; ++ks) {
    bf16x8 ah[4], al[4];
#pragma unroll
    for (int mt = 0; mt < 4; ++mt) {
      int off = (16 * mt + m16) * LDA + ks * 32 + 8 * g;
      ah[mt] = *(const bf16x8*)(Ahi + off);
      al[mt] = *(const bf16x8*)(Alo + off);
    }
#pragma unroll
    for (int nt2 = 0; nt2 < 2; ++nt2) {
      size_t foff = ((size_t)((2 * w + nt2) * KS + ks) * 64 + lane) * 8;
      bf16x8 bh = *(const bf16x8*)(Bhi + foff);
      bf16x8 bl = *(const bf16x8*)(Blo + foff);
#pragma unroll
      for (int mt = 0; mt < 4; ++mt) {
        acc[mt][nt2] = __builtin_amdgcn_mfma_f32_16x16x32_bf16(ah[mt], bh, acc[mt][nt2], 0, 0, 0);
        acc[mt][nt2] = __builtin_amdgcn_mfma_f32_16x16x32_bf16(ah[mt], bl, acc[mt][nt2], 0, 0, 0);
        acc[mt][nt2] = __builtin_amdgcn_mfma_f32_16x16x32_bf16(al[mt], bh, acc[mt][nt2], 0, 0, 0);
      }
    }
  }
}

// tanh + split + store C-frags back to the activation LDS (row-major [64][LDA]).
__device__ __forceinline__ void store_acts8(f32x4 acc[4][2], unsigned short* Ahi,
                                            unsigned short* Alo, int w, int lane) {
  const int m16 = lane & 15, g = lane >> 4;
#pragma unroll
  for (int mt = 0; mt < 4; ++mt)
#pragma unroll
    for (int nt2 = 0; nt2 < 2; ++nt2) {
      int col = (2 * w + nt2) * 16 + m16;
#pragma unroll
      for (int r = 0; r < 4; ++r) {
        int row = 16 * mt + 4 * g + r;
        unsigned short h, l;
        split_bf16(fast_tanh(acc[mt][nt2][r]), h, l);
        Ahi[row * LDA + col] = h;
        Alo[row * LDA + col] = l;
      }
    }
}

// Block-wide reduction of 16 per-row partials over 256 threads (k_vals).
__device__ __forceinline__ void block_reduce16(float part[NL], float* red, int tid) {
#pragma unroll
  for (int d = 1; d < 64; d <<= 1) {
#pragma unroll
    for (int s = 0; s < NL; ++s) part[s] += __shfl_xor(part[s], d, 64);
  }
  __syncthreads();
  if ((tid & 63) == 0) {
    int w = tid >> 6;
#pragma unroll
    for (int s = 0; s < NL; ++s) red[w * NL + s] = part[s];
  }
  __syncthreads();
}

// ---------------------------------------------------------------------------
// k_main: 4 batch rows per block (M=64), 8 waves x 32 cols each.
// ---------------------------------------------------------------------------
__global__ __launch_bounds__(512, 4) void k_main(
    const float* __restrict__ obs,
    const float* __restrict__ eb1, const float* __restrict__ eb2,
    const float* __restrict__ vb1, const float* __restrict__ vb2,
    const unsigned short* __restrict__ wpk,
    float* __restrict__ ome_out) {
  __shared__ __align__(16) unsigned short Ahi[64 * LDA];
  __shared__ __align__(16) unsigned short Alo[64 * LDA];
  __shared__ float att_lds[4 * NL];

  const int tid = threadIdx.x;
  const int w = tid >> 6, lane = tid & 63;
  const int b = blockIdx.x;

  // ---- stage x split into A rows (k<48 real, 48..63 zero) ----
#pragma unroll
  for (int r = 0; r < 4; ++r) {           // self: 64 rows x 32 cols
    int e = r * 512 + tid, m = e >> 5, c = e & 31;
    int srow = (64 * b + m) & (BATCH - 1);
    unsigned short h, l; split_bf16(obs[srow * OBSW + c], h, l);
    Ahi[m * LDA + c] = h; Alo[m * LDA + c] = l;
  }
#pragma unroll
  for (int r = 0; r < 2; ++r) {           // obstacle: 64 rows x 16 cols
    int e = r * 512 + tid, m = e >> 4, kk = e & 15;
    float v = obs[(4 * b + (m >> 4)) * OBSW + 96 + 16 * (m & 15) + kk];
    unsigned short h, l; split_bf16(v, h, l);
    Ahi[m * LDA + 32 + kk] = h; Alo[m * LDA + 32 + kk] = l;
  }
#pragma unroll
  for (int r = 0; r < 2; ++r) {           // zero pad k in [48,64)
    int e = r * 512 + tid, m = e >> 4, kk = e & 15;
    Ahi[m * LDA + 48 + kk] = 0; Alo[m * LDA + 48 + kk] = 0;
  }
  __syncthreads();

  f32x4 acc[4][2];

  // h1 = tanh(x @ enc_w1 + b1)
  mfma_layer8<2>(Ahi, Alo, wpk + E1H, wpk + E1L, eb1, w, lane, acc);
  __syncthreads();
  store_acts8(acc, Ahi, Alo, w, lane);
  __syncthreads();

  // emb = tanh(h1 @ enc_w2 + b2)
  mfma_layer8<8>(Ahi, Alo, wpk + E2H, wpk + E2L, eb2, w, lane, acc);
  __syncthreads();
  store_acts8(acc, Ahi, Alo, w, lane);
  __syncthreads();

  // ---- softmax: wave w<4 owns batch row p=w; waves 4..7 go straight to V1
  // (read-only overlap on A; the post-V1 barrier orders everything) ----
  if (w < 4) {
    const int p = w;
    float part[NL];
#pragma unroll
    for (int s = 0; s < NL; ++s) part[s] = 0.f;
#pragma unroll
    for (int cc = 0; cc < 4; ++cc) {
      int c = cc * 64 + lane;
      float ev[NL], qs = 0.f;
#pragma unroll
      for (int s = 0; s < NL; ++s) {
        int row = 16 * p + s;
        ev[s] = bf16_to_f32(Ahi[row * LDA + c]) + bf16_to_f32(Alo[row * LDA + c]);
        qs += ev[s];
      }
#pragma unroll
      for (int s = 0; s < NL; ++s) part[s] += qs * ev[s];
    }
#pragma unroll
    for (int d = 1; d < 64; d <<= 1) {
#pragma unroll
      for (int s = 0; s < NL; ++s) part[s] += __shfl_xor(part[s], d, 64);
    }
    float sc[NL], mx = -1e30f;
#pragma unroll
    for (int s = 0; s < NL; ++s) {
      sc[s] = part[s] * (1.0f / 256.0f);
      mx = fmaxf(mx, sc[s]);
    }
    float se = 0.f, at[NL];
#pragma unroll
    for (int s = 0; s < NL; ++s) { at[s] = expf(sc[s] - mx); se += at[s]; }
    float inv = 1.0f / se;
    if (lane == 0) {
#pragma unroll
      for (int s = 0; s < NL; ++s) att_lds[p * NL + s] = at[s] * inv;
    }
  }

  // hv = tanh(emb @ val_w1 + b1)
  mfma_layer8<8>(Ahi, Alo, wpk + V1H, wpk + V1L, vb1, w, lane, acc);
  __syncthreads();   // softmax A-reads + att_lds writes complete before overwrite
  store_acts8(acc, Ahi, Alo, w, lane);
  __syncthreads();

  // v = tanh(hv @ val_w2 + b2)
  mfma_layer8<8>(Ahi, Alo, wpk + V2H, wpk + V2L, vb2, w, lane, acc);
  __syncthreads();
  store_acts8(acc, Ahi, Alo, w, lane);
  __syncthreads();

  // ---- ome: 2 outputs per thread: (p0, col) and (p0+2, col)
  {
    int col = tid & 255, p0 = tid >> 8;
#pragma unroll
    for (int pp = 0; pp < 2; ++pp) {
      int p = p0 + 2 * pp;
      float o = 0.f;
#pragma unroll
      for (int s = 0; s < NL; ++s) {
        int row = 16 * p + s;
        float vv = bf16_to_f32(Ahi[row * LDA + col]) + bf16_to_f32(Alo[row * LDA + col]);
        o += att_lds[p * NL + s] * vv;
      }
      ome_out[(size_t)(4 * b + p) * HD + col] = o;
    }
  }
}

// ---------------------------------------------------------------------------
// k_vals (unchanged): fp32 VALU mlp2 + layernorm
// ---------------------------------------------------------------------------
#define PADW 20
template<int K>
__device__ __forceinline__ void qgemm_read(const float* inT, const float* __restrict__ W,
                                           const float* __restrict__ bias,
                                           int jq, int sq, float acc[4][4]) {
  {
    const float4 bb = *(const float4*)(bias + 4 * jq);
    const float b4[4] = {bb.x, bb.y, bb.z, bb.w};
#pragma unroll
    for (int si = 0; si < 4; ++si)
#pragma unroll
      for (int ji = 0; ji < 4; ++ji) acc[si][ji] = b4[ji];
  }
  const float* arow = inT + 4 * sq;
  const float* wrow = W + 4 * jq;
#pragma unroll 4
  for (int k = 0; k < K; ++k) {
    const float4 av = *(const float4*)(arow + k * PADW);
    const float4 wv = *(const float4*)(wrow + (size_t)k * HD);
    const float a4[4] = {av.x, av.y, av.z, av.w};
    const float w4[4] = {wv.x, wv.y, wv.z, wv.w};
#pragma unroll
    for (int si = 0; si < 4; ++si)
#pragma unroll
      for (int ji = 0; ji < 4; ++ji) acc[si][ji] = fmaf(a4[si], w4[ji], acc[si][ji]);
  }
}
__device__ __forceinline__ void write_tile_tanh(float* outT, int jq, int sq,
                                                const float acc[4][4]) {
#pragma unroll
  for (int ji = 0; ji < 4; ++ji) {
    float4 o;
    o.x = fast_tanh(acc[0][ji]); o.y = fast_tanh(acc[1][ji]);
    o.z = fast_tanh(acc[2][ji]); o.w = fast_tanh(acc[3][ji]);
    *(float4*)(outT + (4 * jq + ji) * PADW + 4 * sq) = o;
  }
}
__device__ __forceinline__ void read_col16(const float* buf, int j, float v[NL]) {
  const float4* p = (const float4*)(buf + j * PADW);
  float4 a0 = p[0], a1 = p[1], a2 = p[2], a3 = p[3];
  v[0]=a0.x; v[1]=a0.y; v[2]=a0.z; v[3]=a0.w; v[4]=a1.x; v[5]=a1.y; v[6]=a1.z; v[7]=a1.w;
  v[8]=a2.x; v[9]=a2.y; v[10]=a2.z; v[11]=a2.w; v[12]=a3.x; v[13]=a3.y; v[14]=a3.z; v[15]=a3.w;
}
__global__ __launch_bounds__(256, 8) void k_vals(
    const float* __restrict__ ome,
    const float* __restrict__ w1, const float* __restrict__ b1,
    const float* __restrict__ w2, const float* __restrict__ b2,
    const float* __restrict__ lng, const float* __restrict__ lnb,
    float* __restrict__ ov) {
  __shared__ __align__(16) float buf[HD * PADW];
  __shared__ float red[4 * NL];
  const int j = threadIdx.x, jq = j >> 2, sq = j & 3;
  const int r0 = blockIdx.x * NL;
#pragma unroll
  for (int i = 0; i < NL; ++i) {
    int e = i * 256 + j, r = e >> 8, k = e & 255;
    buf[k * PADW + r] = ome[(size_t)(r0 + r) * HD + k];
  }
  __syncthreads();
  float acc[4][4];
  qgemm_read<HD>(buf, w1, b1, jq, sq, acc);
  __syncthreads();
  write_tile_tanh(buf, jq, sq, acc);
  __syncthreads();
  qgemm_read<HD>(buf, w2, b2, jq, sq, acc);
  __syncthreads();
  write_tile_tanh(buf, jq, sq, acc);
  __syncthreads();
  float o0[NL];
  read_col16(buf, j, o0);
  float part[NL];
#pragma unroll
  for (int s = 0; s < NL; ++s) part[s] = o0[s];
  block_reduce16(part, red, j);
  float mu[NL];
#pragma unroll
  for (int s = 0; s < NL; ++s)
    mu[s] = (red[s] + red[NL + s] + red[2 * NL + s] + red[3 * NL + s]) * (1.0f / 256.0f);
#pragma unroll
  for (int s = 0; s < NL; ++s) { float d = o0[s] - mu[s]; part[s] = d * d; }
  block_reduce16(part, red, j);
  float gv = lng[j], bv = lnb[j];
#pragma unroll
  for (int s = 0; s < NL; ++s) {
    float var = (red[s] + red[NL + s] + red[2 * NL + s] + red[3 * NL + s]) * (1.0f / 256.0f);
    ov[(size_t)(r0 + s) * HD + j] = (o0[s] - mu[s]) * rsqrtf(var + 1e-6f) * gv + bv;
  }
}

// ---------------------------------------------------------------------------
// k_group (unchanged): group attention + tile x4 output
// ---------------------------------------------------------------------------
__global__ __launch_bounds__(256) void k_group(
    const float* __restrict__ ome,
    const float* __restrict__ ov,
    float* __restrict__ out) {
  const int g = blockIdx.x, j = threadIdx.x;
  float m[4], o[4];
#pragma unroll
  for (int p = 0; p < 4; ++p) {
    m[p] = ome[(size_t)(g * 4 + p) * HD + j];
    o[p] = ov[(size_t)(g * 4 + p) * HD + j];
  }
  float qv = (m[0] + m[1] + m[2] + m[3]) * 0.25f * 0.17677669529663687f;
  float sc[4];
#pragma unroll
  for (int p = 0; p < 4; ++p) {
    float t = qv * m[p];
#pragma unroll
    for (int d = 1; d < 32; d <<= 1) t += __shfl_xor(t, d, 64);
    sc[p] = t;
  }
  float mx = fmaxf(fmaxf(sc[0], sc[1]), fmaxf(sc[2], sc[3]));
  float e[4], se = 0.f;
#pragma unroll
  for (int p = 0; p < 4; ++p) { e[p] = expf(sc[p] - mx); se += e[p]; }
  float inv = 1.0f / se, r = 0.f;
#pragma unroll
  for (int p = 0; p < 4; ++p) r += e[p] * inv * o[p];
#pragma unroll
  for (int rep = 0; rep < 4; ++rep) out[(size_t)(rep * G_NUM + g) * HD + j] = r;
}

// ---------------------------------------------------------------------------
extern "C" void kernel_launch(void* const* d_in, const int* in_sizes, int n_in,
                              void* d_out, int out_size, void* d_ws, size_t ws_size,
                              hipStream_t stream) {
  const float* obs = (const float*)d_in[0];
  const float* ew1 = (const float*)d_in[1];
  const float* eb1 = (const float*)d_in[2];
  const float* ew2 = (const float*)d_in[3];
  const float* eb2 = (const float*)d_in[4];
  const float* vw1 = (const float*)d_in[5];
  const float* vb1 = (const float*)d_in[6];
  const float* vw2 = (const float*)d_in[7];
  const float* vb2 = (const float*)d_in[8];
  const float* sw1 = (const float*)d_in[9];
  const float* sb1 = (const float*)d_in[10];
  const float* sw2 = (const float*)d_in[11];
  const float* sb2 = (const float*)d_in[12];
  const float* lng = (const float*)d_in[13];
  const float* lnb = (const float*)d_in[14];

  float* out = (float*)d_out;
  float* ome = out + (size_t)BATCH * HD;   // output 2 region (also consumed below)
  float* ov  = (float*)d_ws;               // 16.78 MB

  const size_t OV_BYTES = (size_t)BATCH * HD * 4;
  const size_t PACK_BYTES = (size_t)PACK_ELEMS * 2;
  unsigned short* wpk;
  if (ws_size >= OV_BYTES + PACK_BYTES)
    wpk = (unsigned short*)((char*)d_ws + OV_BYTES);
  else
    wpk = (unsigned short*)d_out;  // first 832 KB of out; fully overwritten by k_group later

  k_pack<<<416, 64, 0, stream>>>(ew1, ew2, vw1, vw2, wpk);
  k_main<<<G_NUM, 512, 0, stream>>>(obs, eb1, eb2, vb1, vb2, wpk, ome);
  k_vals<<<BATCH / NL, 256, 0, stream>>>(ome, sw1, sb1, sw2, sb2, lng, lnb, ov);
  k_group<<<G_NUM, 256, 0, stream>>>(ome, ov, out);
}

// Round 12
// 441.811 us; speedup vs baseline: 4.2854x; 1.1550x over previous
//
#include <hip/hip_runtime.h>
#include <hip/hip_bf16.h>
#include <math.h>

#define BATCH   16384
#define G_NUM   4096
#define NL      16
#define HD      256
#define OBSW    480
#define LDA     264      // ushort stride of activation LDS rows (528B: 16B-aligned)

using bf16x8 = __attribute__((ext_vector_type(8))) short;   // 8 bf16 = 4 VGPRs
using f32x4  = __attribute__((ext_vector_type(4))) float;

// Packed-weight element offsets (ushort units) inside wpk:
// per matrix: [tile(16)][ks][lane(64)][8] bf16, hi then lo.
#define E1H 0
#define E1L 16384
#define E2H 32768
#define E2L 98304
#define V1H 163840
#define V1L 229376
#define V2H 294912
#define V2L 360448
#define S1H 425984
#define S1L 491520
#define S2H 557056
#define S2L 622592
#define PACK_ELEMS 688128  // 1.31 MB

__device__ __forceinline__ float fast_tanh(float x) {
  float e = __expf(2.0f * x);
  return 1.0f - 2.0f * __builtin_amdgcn_rcpf(e + 1.0f);
}

__device__ __forceinline__ unsigned short f32_to_bf16(float x) {
  unsigned u = __float_as_uint(x);
  return (unsigned short)((u + 0x7fffu + ((u >> 16) & 1u)) >> 16);
}
__device__ __forceinline__ float bf16_to_f32(unsigned short h) {
  return __uint_as_float(((unsigned)h) << 16);
}
// Rounding split (k_pack only: one-time, max precision).
__device__ __forceinline__ void split_bf16(float x, unsigned short& hi, unsigned short& lo) {
  hi = f32_to_bf16(x);
  lo = f32_to_bf16(x - bf16_to_f32(hi));
}
// Truncation split (hot paths): hi = top16(x) (mask), lo = top16(x - hi).
// |x - hi - lo| <= 2^-16 |x|; ~3 VALU vs ~10, and (u>>16) u16 stores fold to
// ds_write_b16_d16_hi.
__device__ __forceinline__ void split_trunc(float x, unsigned short& hi, unsigned short& lo) {
  unsigned u = __float_as_uint(x);
  float hif = __uint_as_float(u & 0xffff0000u);
  hi = (unsigned short)(u >> 16);
  lo = (unsigned short)(__float_as_uint(x - hif) >> 16);
}

// ---------------------------------------------------------------------------
// k_pack: repack fp32 weights [K][256] into MFMA B-fragment order, split hi/lo.
// Fragment: lane l holds B[k0 + 8*(l>>4) + i][c0 + (l&15)], i=0..7 contiguous.
// ---------------------------------------------------------------------------
__global__ void k_pack(const float* __restrict__ ew1, const float* __restrict__ ew2,
                       const float* __restrict__ vw1, const float* __restrict__ vw2,
                       const float* __restrict__ sw1, const float* __restrict__ sw2,
                       unsigned short* __restrict__ wpk) {
  int bid = blockIdx.x, lane = threadIdx.x;
  const float* W; int KS, K, baseh, basel;
  if (bid < 32)       { W = ew1; KS = 2; K = 48;  baseh = E1H; basel = E1L; }
  else if (bid < 160) { W = ew2; KS = 8; K = 256; baseh = E2H; basel = E2L; bid -= 32; }
  else if (bid < 288) { W = vw1; KS = 8; K = 256; baseh = V1H; basel = V1L; bid -= 160; }
  else if (bid < 416) { W = vw2; KS = 8; K = 256; baseh = V2H; basel = V2L; bid -= 288; }
  else if (bid < 544) { W = sw1; KS = 8; K = 256; baseh = S1H; basel = S1L; bid -= 416; }
  else                { W = sw2; KS = 8; K = 256; baseh = S2H; basel = S2L; bid -= 544; }
  int t = bid & 15, ks = bid >> 4;
  int g = lane >> 4, c = t * 16 + (lane & 15);
  unsigned short hv[8], lv[8];
#pragma unroll
  for (int i = 0; i < 8; ++i) {
    int k = ks * 32 + g * 8 + i;
    float v = (k < K) ? W[k * HD + c] : 0.f;
    split_bf16(v, hv[i], lv[i]);
  }
  size_t off = ((size_t)(t * KS + ks) * 64 + lane) * 8;
#pragma unroll
  for (int i = 0; i < 8; ++i) { wpk[baseh + off + i] = hv[i]; wpk[basel + off + i] = lv[i]; }
}

// ---------------------------------------------------------------------------
// 3-term split-bf16 MFMA layer: wave w owns cols 32w..32w+31 (nt = 2w+nt2).
// MT = number of 16-row tiles (MT=4 -> 64 rows, MT=2 -> 32 rows).
// ---------------------------------------------------------------------------
template<int KS, int MT>
__device__ __forceinline__ void mfma_layer8(const unsigned short* Ahi, const unsigned short* Alo,
                                            const unsigned short* __restrict__ Bhi,
                                            const unsigned short* __restrict__ Blo,
                                            const float* __restrict__ bias,
                                            int w, int lane, f32x4 acc[MT][2]) {
  const int m16 = lane & 15, g = lane >> 4;
#pragma unroll
  for (int nt2 = 0; nt2 < 2; ++nt2) {
    float b = bias[(2 * w + nt2) * 16 + m16];   // D col = lane&15
#pragma unroll
    for (int mt = 0; mt < MT; ++mt) {
      acc[mt][nt2][0] = b; acc[mt][nt2][1] = b; acc[mt][nt2][2] = b; acc[mt][nt2][3] = b;
    }
  }
#pragma unroll 2
  for (int ks = 0; ks < KS; ++ks) {
    bf16x8 ah[MT], al[MT];
#pragma unroll
    for (int mt = 0; mt < MT; ++mt) {
      int off = (16 * mt + m16) * LDA + ks * 32 + 8 * g;
      ah[mt] = *(const bf16x8*)(Ahi + off);
      al[mt] = *(const bf16x8*)(Alo + off);
    }
#pragma unroll
    for (int nt2 = 0; nt2 < 2; ++nt2) {
      size_t foff = ((size_t)((2 * w + nt2) * KS + ks) * 64 + lane) * 8;
      bf16x8 bh = *(const bf16x8*)(Bhi + foff);
      bf16x8 bl = *(const bf16x8*)(Blo + foff);
#pragma unroll
      for (int mt = 0; mt < MT; ++mt) {
        acc[mt][nt2] = __builtin_amdgcn_mfma_f32_16x16x32_bf16(ah[mt], bh, acc[mt][nt2], 0, 0, 0);
        acc[mt][nt2] = __builtin_amdgcn_mfma_f32_16x16x32_bf16(ah[mt], bl, acc[mt][nt2], 0, 0, 0);
        acc[mt][nt2] = __builtin_amdgcn_mfma_f32_16x16x32_bf16(al[mt], bh, acc[mt][nt2], 0, 0, 0);
      }
    }
  }
}

// tanh + trunc-split + store C-frags back to the activation LDS.
template<int MT>
__device__ __forceinline__ void store_acts8(f32x4 acc[MT][2], unsigned short* Ahi,
                                            unsigned short* Alo, int w, int lane) {
  const int m16 = lane & 15, g = lane >> 4;
#pragma unroll
  for (int mt = 0; mt < MT; ++mt)
#pragma unroll
    for (int nt2 = 0; nt2 < 2; ++nt2) {
      int col = (2 * w + nt2) * 16 + m16;
#pragma unroll
      for (int r = 0; r < 4; ++r) {
        int row = 16 * mt + 4 * g + r;
        unsigned short h, l;
        split_trunc(fast_tanh(acc[mt][nt2][r]), h, l);
        Ahi[row * LDA + col] = h;
        Alo[row * LDA + col] = l;
      }
    }
}

// ---------------------------------------------------------------------------
// k_main: 4 batch rows per block (M=64), 8 waves x 32 cols each.
// ---------------------------------------------------------------------------
__global__ __launch_bounds__(512, 4) void k_main(
    const float* __restrict__ obs,
    const float* __restrict__ eb1, const float* __restrict__ eb2,
    const float* __restrict__ vb1, const float* __restrict__ vb2,
    const unsigned short* __restrict__ wpk,
    float* __restrict__ ome_out) {
  __shared__ __align__(16) unsigned short Ahi[64 * LDA];
  __shared__ __align__(16) unsigned short Alo[64 * LDA];
  __shared__ float att_lds[4 * NL];

  const int tid = threadIdx.x;
  const int w = tid >> 6, lane = tid & 63;
  const int b = blockIdx.x;

  // ---- stage x split into A rows (k<48 real, 48..63 zero) ----
#pragma unroll
  for (int r = 0; r < 4; ++r) {           // self: 64 rows x 32 cols
    int e = r * 512 + tid, m = e >> 5, c = e & 31;
    int srow = (64 * b + m) & (BATCH - 1);
    unsigned short h, l; split_trunc(obs[srow * OBSW + c], h, l);
    Ahi[m * LDA + c] = h; Alo[m * LDA + c] = l;
  }
#pragma unroll
  for (int r = 0; r < 2; ++r) {           // obstacle: 64 rows x 16 cols
    int e = r * 512 + tid, m = e >> 4, kk = e & 15;
    float v = obs[(4 * b + (m >> 4)) * OBSW + 96 + 16 * (m & 15) + kk];
    unsigned short h, l; split_trunc(v, h, l);
    Ahi[m * LDA + 32 + kk] = h; Alo[m * LDA + 32 + kk] = l;
  }
#pragma unroll
  for (int r = 0; r < 2; ++r) {           // zero pad k in [48,64)
    int e = r * 512 + tid, m = e >> 4, kk = e & 15;
    Ahi[m * LDA + 48 + kk] = 0; Alo[m * LDA + 48 + kk] = 0;
  }
  __syncthreads();

  f32x4 acc[4][2];

  // h1 = tanh(x @ enc_w1 + b1)
  mfma_layer8<2, 4>(Ahi, Alo, wpk + E1H, wpk + E1L, eb1, w, lane, acc);
  __syncthreads();
  store_acts8<4>(acc, Ahi, Alo, w, lane);
  __syncthreads();

  // emb = tanh(h1 @ enc_w2 + b2)
  mfma_layer8<8, 4>(Ahi, Alo, wpk + E2H, wpk + E2L, eb2, w, lane, acc);
  __syncthreads();
  store_acts8<4>(acc, Ahi, Alo, w, lane);
  __syncthreads();

  // ---- softmax: wave w<4 owns batch row p=w; waves 4..7 go straight to V1
  // (read-only overlap on A; the post-V1 barrier orders everything) ----
  if (w < 4) {
    const int p = w;
    float part[NL];
#pragma unroll
    for (int s = 0; s < NL; ++s) part[s] = 0.f;
#pragma unroll
    for (int cc = 0; cc < 4; ++cc) {
      int c = cc * 64 + lane;
      float ev[NL], qs = 0.f;
#pragma unroll
      for (int s = 0; s < NL; ++s) {
        int row = 16 * p + s;
        ev[s] = bf16_to_f32(Ahi[row * LDA + c]) + bf16_to_f32(Alo[row * LDA + c]);
        qs += ev[s];
      }
#pragma unroll
      for (int s = 0; s < NL; ++s) part[s] += qs * ev[s];
    }
#pragma unroll
    for (int d = 1; d < 64; d <<= 1) {
#pragma unroll
      for (int s = 0; s < NL; ++s) part[s] += __shfl_xor(part[s], d, 64);
    }
    float sc[NL], mx = -1e30f;
#pragma unroll
    for (int s = 0; s < NL; ++s) {
      sc[s] = part[s] * (1.0f / 256.0f);
      mx = fmaxf(mx, sc[s]);
    }
    float se = 0.f, at[NL];
#pragma unroll
    for (int s = 0; s < NL; ++s) { at[s] = expf(sc[s] - mx); se += at[s]; }
    float inv = 1.0f / se;
    if (lane == 0) {
#pragma unroll
      for (int s = 0; s < NL; ++s) att_lds[p * NL + s] = at[s] * inv;
    }
  }

  // hv = tanh(emb @ val_w1 + b1)
  mfma_layer8<8, 4>(Ahi, Alo, wpk + V1H, wpk + V1L, vb1, w, lane, acc);
  __syncthreads();   // softmax A-reads + att_lds writes complete before overwrite
  store_acts8<4>(acc, Ahi, Alo, w, lane);
  __syncthreads();

  // v = tanh(hv @ val_w2 + b2)
  mfma_layer8<8, 4>(Ahi, Alo, wpk + V2H, wpk + V2L, vb2, w, lane, acc);
  __syncthreads();
  store_acts8<4>(acc, Ahi, Alo, w, lane);
  __syncthreads();

  // ---- ome: 2 outputs per thread: (p0, col) and (p0+2, col)
  {
    int col = tid & 255, p0 = tid >> 8;
#pragma unroll
    for (int pp = 0; pp < 2; ++pp) {
      int p = p0 + 2 * pp;
      float o = 0.f;
#pragma unroll
      for (int s = 0; s < NL; ++s) {
        int row = 16 * p + s;
        float vv = bf16_to_f32(Ahi[row * LDA + col]) + bf16_to_f32(Alo[row * LDA + col]);
        o += att_lds[p * NL + s] * vv;
      }
      ome_out[(size_t)(4 * b + p) * HD + col] = o;
    }
  }
}

// ---------------------------------------------------------------------------
// k_vals_mm: 32 ome rows per block (512 blocks), MFMA mlp2 + fused layernorm.
// ---------------------------------------------------------------------------
__global__ __launch_bounds__(512, 4) void k_vals_mm(
    const float* __restrict__ ome,
    const float* __restrict__ sb1, const float* __restrict__ sb2,
    const float* __restrict__ lng, const float* __restrict__ lnb,
    const unsigned short* __restrict__ wpk,
    float* __restrict__ ov) {
  __shared__ __align__(16) unsigned short Ahi[32 * LDA];
  __shared__ __align__(16) unsigned short Alo[32 * LDA];

  const int tid = threadIdx.x;
  const int w = tid >> 6, lane = tid & 63;
  const int b = blockIdx.x;

  // stage 32 rows of ome (split)
#pragma unroll
  for (int r = 0; r < 16; ++r) {
    int e = r * 512 + tid, row = e >> 8, col = e & 255;
    unsigned short h, l; split_trunc(ome[(size_t)(32 * b + row) * HD + col], h, l);
    Ahi[row * LDA + col] = h; Alo[row * LDA + col] = l;
  }
  __syncthreads();

  f32x4 acc[2][2];
  mfma_layer8<8, 2>(Ahi, Alo, wpk + S1H, wpk + S1L, sb1, w, lane, acc);
  __syncthreads();
  store_acts8<2>(acc, Ahi, Alo, w, lane);
  __syncthreads();
  mfma_layer8<8, 2>(Ahi, Alo, wpk + S2H, wpk + S2L, sb2, w, lane, acc);
  __syncthreads();
  store_acts8<2>(acc, Ahi, Alo, w, lane);
  __syncthreads();

  // ---- layernorm: row = tid>>4 (16 threads/row, 16 cols each) ----
  const int row = tid >> 4, c0 = (tid & 15) * 16;
  float v[16], s = 0.f;
#pragma unroll
  for (int i = 0; i < 16; ++i) {
    int c = c0 + i;
    v[i] = bf16_to_f32(Ahi[row * LDA + c]) + bf16_to_f32(Alo[row * LDA + c]);
    s += v[i];
  }
#pragma unroll
  for (int d = 1; d < 16; d <<= 1) s += __shfl_xor(s, d, 64);
  float mu = s * (1.0f / 256.0f);
  float q = 0.f;
#pragma unroll
  for (int i = 0; i < 16; ++i) { float dd = v[i] - mu; q += dd * dd; }
#pragma unroll
  for (int d = 1; d < 16; d <<= 1) q += __shfl_xor(q, d, 64);
  float rsq = rsqrtf(q * (1.0f / 256.0f) + 1e-6f);
#pragma unroll
  for (int i = 0; i < 16; ++i) {
    int c = c0 + i;
    float y = (v[i] - mu) * rsq * lng[c] + lnb[c];
    ov[(size_t)(32 * b + row) * HD + c] = y;
  }
}

// ---------------------------------------------------------------------------
// k_group (unchanged): group attention + tile x4 output
// ---------------------------------------------------------------------------
__global__ __launch_bounds__(256) void k_group(
    const float* __restrict__ ome,
    const float* __restrict__ ov,
    float* __restrict__ out) {
  const int g = blockIdx.x, j = threadIdx.x;
  float m[4], o[4];
#pragma unroll
  for (int p = 0; p < 4; ++p) {
    m[p] = ome[(size_t)(g * 4 + p) * HD + j];
    o[p] = ov[(size_t)(g * 4 + p) * HD + j];
  }
  float qv = (m[0] + m[1] + m[2] + m[3]) * 0.25f * 0.17677669529663687f;
  float sc[4];
#pragma unroll
  for (int p = 0; p < 4; ++p) {
    float t = qv * m[p];
#pragma unroll
    for (int d = 1; d < 32; d <<= 1) t += __shfl_xor(t, d, 64);
    sc[p] = t;
  }
  float mx = fmaxf(fmaxf(sc[0], sc[1]), fmaxf(sc[2], sc[3]));
  float e[4], se = 0.f;
#pragma unroll
  for (int p = 0; p < 4; ++p) { e[p] = expf(sc[p] - mx); se += e[p]; }
  float inv = 1.0f / se, r = 0.f;
#pragma unroll
  for (int p = 0; p < 4; ++p) r += e[p] * inv * o[p];
#pragma unroll
  for (int rep = 0; rep < 4; ++rep) out[(size_t)(rep * G_NUM + g) * HD + j] = r;
}

// ---------------------------------------------------------------------------
extern "C" void kernel_launch(void* const* d_in, const int* in_sizes, int n_in,
                              void* d_out, int out_size, void* d_ws, size_t ws_size,
                              hipStream_t stream) {
  const float* obs = (const float*)d_in[0];
  const float* ew1 = (const float*)d_in[1];
  const float* eb1 = (const float*)d_in[2];
  const float* ew2 = (const float*)d_in[3];
  const float* eb2 = (const float*)d_in[4];
  const float* vw1 = (const float*)d_in[5];
  const float* vb1 = (const float*)d_in[6];
  const float* vw2 = (const float*)d_in[7];
  const float* vb2 = (const float*)d_in[8];
  const float* sw1 = (const float*)d_in[9];
  const float* sb1 = (const float*)d_in[10];
  const float* sw2 = (const float*)d_in[11];
  const float* sb2 = (const float*)d_in[12];
  const float* lng = (const float*)d_in[13];
  const float* lnb = (const float*)d_in[14];

  float* out = (float*)d_out;
  float* ome = out + (size_t)BATCH * HD;   // output 2 region (also consumed below)
  float* ov  = (float*)d_ws;               // 16.78 MB

  const size_t OV_BYTES = (size_t)BATCH * HD * 4;
  const size_t PACK_BYTES = (size_t)PACK_ELEMS * 2;
  unsigned short* wpk;
  if (ws_size >= OV_BYTES + PACK_BYTES)
    wpk = (unsigned short*)((char*)d_ws + OV_BYTES);
  else
    wpk = (unsigned short*)d_out;  // first 1.31 MB of out0; free until k_group writes it

  k_pack<<<672, 64, 0, stream>>>(ew1, ew2, vw1, vw2, sw1, sw2, wpk);
  k_main<<<G_NUM, 512, 0, stream>>>(obs, eb1, eb2, vb1, vb2, wpk, ome);
  k_vals_mm<<<BATCH / 32, 512, 0, stream>>>(ome, sb1, sb2, lng, lnb, wpk, ov);
  k_group<<<G_NUM, 256, 0, stream>>>(ome, ov, out);
}